// Round 3
// baseline (104.687 us; speedup 1.0000x reference)
//
#include <hip/hip_runtime.h>
#include <math.h>

#define NNODES 512
#define CIN 8
#define COUT 8
#define RR 8
#define GUARD 64                       // zeroed guard node-slots each side
#define SLOTS (GUARD + NNODES + GUARD) // 640 node slots per bt
#define SLAB_HW (SLOTS * 8)            // 5120 halfwords (16 B per node slot)
#define WTAB 1024                      // float offset of addr table in ws

typedef __attribute__((ext_vector_type(8))) short short8;
typedef __attribute__((ext_vector_type(4))) float floatx4;

__device__ __forceinline__ unsigned int pack_bf16(float a, float b) {
    unsigned int ua = __float_as_uint(a);
    unsigned int ub = __float_as_uint(b);
    ua = (ua + 0x7fffu + ((ua >> 16) & 1u)) >> 16;
    ub = (ub + 0x7fffu + ((ub >> 16) & 1u)) & 0xffff0000u;
    return ua | ub;
}

// ---- prep (PARALLEL: 12 blocks x 256): fold sigmoid(alpha) into weights/bias
// + per-(t,lane) LDS byte-offset table.
// ws floats [0..959]:  w[o][c][15] (0..6 = a*stencil taps, 7..14 = (1-a)*mix_w)
//          [960..967]: bias2[o]
// ws ints  [1024..1024+8192): int4 table[t*64+lane] = LDS byte offsets for MFMA i=0..3
// K = tap*8 + c. MFMA i covers taps {4i..4i+3}; quad q holds tap 4i+q.
// taps: 0 center, 1 d-, 2 d+, 3 h-, 4 h+, 5 w-, 6 w+, 7..14 g0..g7, 15 zero.
__global__ __launch_bounds__(256) void prep(
                     const float* __restrict__ conv_w,
                     const float* __restrict__ conv_b,
                     const float* __restrict__ mix_w,
                     const float* __restrict__ mix_b,
                     const float* __restrict__ alpha_p,
                     const int*   __restrict__ rand_idx,
                     float* __restrict__ ws) {
    const int gid = blockIdx.x * 256 + threadIdx.x;
    const float a = 1.0f / (1.0f + expf(-alpha_p[0]));

    if (gid < 2048) {
        // table entries (blocks 0..7)
        const int e = gid;
        const int tt = e >> 6, lane = e & 63;
        const int q = lane >> 4, r16 = lane & 15;
        const int m = tt * 16 + r16;
        const int h = (m >> 3) & 7, w = m & 7;
        int off[4];
#pragma unroll
        for (int i = 0; i < 4; ++i) {
            const int tap = 4 * i + q;
            int o;
            if (tap == 0)       o = GUARD + m;
            else if (tap == 1)  o = GUARD + m - 64;                    // d- (guard zero)
            else if (tap == 2)  o = GUARD + m + 64;                    // d+
            else if (tap == 3)  o = (h > 0) ? (GUARD + m - 8) : 0;     // h-
            else if (tap == 4)  o = (h < 7) ? (GUARD + m + 8) : 0;     // h+
            else if (tap == 5)  o = (w > 0) ? (GUARD + m - 1) : 0;     // w-
            else if (tap == 6)  o = (w < 7) ? (GUARD + m + 1) : 0;     // w+
            else if (tap <= 14) o = GUARD + rand_idx[m * RR + (tap - 7)];
            else                o = 0;                                 // tap15 -> zero slot
            off[i] = o * 16;   // bytes (16 B per node slot)
        }
        int4* tab = (int4*)((int*)ws + WTAB);
        tab[e] = make_int4(off[0], off[1], off[2], off[3]);
    } else {
        // weight/bias fold (blocks 8..11)
        const int k = gid - 2048;
        if (k < 960) {
            const int oc = k / 15;
            const int tap = k % 15;
            float v;
            if (tap < 7) {
                // (kd,kh,kw)->kd*9+kh*3+kw: center=13, d-=4, d+=22, h-=10, h+=16, w-=12, w+=14
                const int off7[7] = {13, 4, 22, 10, 16, 12, 14};
                v = a * conv_w[oc * 27 + off7[tap]];
            } else {
                v = (1.0f - a) * mix_w[oc * RR + (tap - 7)];
            }
            ws[k] = v;
        } else if (k < 968) {
            const int o = k - 960;
            ws[960 + o] = a * conv_b[o] + (1.0f - a) * mix_b[o];
        }
    }
}

// ---- main: BTB=1 (128 threads, 2 waves, one bt-slab per block).
// Staging HBM loads issued FIRST (latency overlaps guard-zero + bfrag build).
__global__ __launch_bounds__(128) void hybrid3d_v6(
    const float* __restrict__ x,
    const float* __restrict__ wsb,
    float* __restrict__ out)
{
    __shared__ unsigned short lds16[SLAB_HW];
    const int tid  = threadIdx.x;
    const int half = tid >> 6;      // wave = node-half handled
    const int lane = tid & 63;
    const int quad = lane >> 4;
    const int r16  = lane & 15;

    // ---- issue staging loads first: 32 scalar coalesced loads per thread
    const float* xg = x + (size_t)blockIdx.x * (CIN * NNODES);
    float v[4][8];
#pragma unroll
    for (int j = 0; j < 4; ++j) {
        const int n = half * 256 + j * 64 + lane;
#pragma unroll
        for (int c = 0; c < 8; ++c) v[j][c] = xg[c * NNODES + n];
    }

    // guard slots: 128 slots x 16 B -> exactly one uint4 per thread
    {
        const int slot = (tid < GUARD) ? tid : (NNODES + tid);  // 0..63 | 576..639
        *(uint4*)&lds16[slot * 8] = make_uint4(0u, 0u, 0u, 0u);
    }

    // B-fragments (weights) + bias (L1/L2-resident; overlaps x-load latency)
    short8 bfrag[4];
#pragma unroll
    for (int i = 0; i < 4; ++i) {
        const int tap = 4 * i + quad;
        union { unsigned int u[4]; short8 s; } bf;
#pragma unroll
        for (int jp = 0; jp < 4; ++jp) {
            const int c0 = 2 * jp, c1 = 2 * jp + 1;
            float f0 = (r16 < 8 && tap < 15) ? wsb[(r16 * CIN + c0) * 15 + tap] : 0.0f;
            float f1 = (r16 < 8 && tap < 15) ? wsb[(r16 * CIN + c1) * 15 + tap] : 0.0f;
            bf.u[jp] = pack_bf16(f0, f1);
        }
        bfrag[i] = bf.s;
    }
    const float bias = (r16 < 8) ? wsb[960 + r16] : 0.0f;

    // pack + LDS write (node-major bf16 slots)
#pragma unroll
    for (int j = 0; j < 4; ++j) {
        const int n = half * 256 + j * 64 + lane;
        uint4 pk;
        pk.x = pack_bf16(v[j][0], v[j][1]);
        pk.y = pack_bf16(v[j][2], v[j][3]);
        pk.z = pack_bf16(v[j][4], v[j][5]);
        pk.w = pack_bf16(v[j][6], v[j][7]);
        *(uint4*)&lds16[(GUARD + n) * 8] = pk;
    }

    // first table entry prefetch before the barrier (global, independent of LDS)
    const int4* tab = (const int4*)((const int*)wsb + WTAB);
    int4 off = tab[(half * 16) * 64 + lane];

    __syncthreads();

    const char* slabp = (const char*)lds16;
    float* outb = out + (size_t)blockIdx.x * (COUT * NNODES);

#pragma unroll 4
    for (int tt = 0; tt < 16; ++tt) {
        const int t = half * 16 + tt;
        const int4 cur = off;
        if (tt < 15) off = tab[(t + 1) * 64 + lane];

        union { uint4 u; short8 s; } r0, r1, r2, r3;  // 4x ds_read_b128
        r0.u = *(const uint4*)(slabp + cur.x);
        r1.u = *(const uint4*)(slabp + cur.y);
        r2.u = *(const uint4*)(slabp + cur.z);
        r3.u = *(const uint4*)(slabp + cur.w);

        floatx4 acc_a = {bias, bias, bias, bias};
        floatx4 acc_b = {0.0f, 0.0f, 0.0f, 0.0f};
        acc_a = __builtin_amdgcn_mfma_f32_16x16x32_bf16(r0.s, bfrag[0], acc_a, 0, 0, 0);
        acc_b = __builtin_amdgcn_mfma_f32_16x16x32_bf16(r2.s, bfrag[2], acc_b, 0, 0, 0);
        acc_a = __builtin_amdgcn_mfma_f32_16x16x32_bf16(r1.s, bfrag[1], acc_a, 0, 0, 0);
        acc_b = __builtin_amdgcn_mfma_f32_16x16x32_bf16(r3.s, bfrag[3], acc_b, 0, 0, 0);

        // C/D: col=lane&15 (=o), row=quad*4+reg (node within 16-tile)
        if (r16 < 8) {
            float4 res;
            res.x = acc_a.x + acc_b.x;
            res.y = acc_a.y + acc_b.y;
            res.z = acc_a.z + acc_b.z;
            res.w = acc_a.w + acc_b.w;
            *(float4*)(outb + r16 * NNODES + t * 16 + quad * 4) = res;
        }
    }
}

extern "C" void kernel_launch(void* const* d_in, const int* in_sizes, int n_in,
                              void* d_out, int out_size, void* d_ws, size_t ws_size,
                              hipStream_t stream) {
    const float* x       = (const float*)d_in[0];
    const float* conv_w  = (const float*)d_in[1];
    const float* conv_b  = (const float*)d_in[2];
    const float* mix_w   = (const float*)d_in[3];
    const float* mix_b   = (const float*)d_in[4];
    const float* alpha_p = (const float*)d_in[5];
    const int*   rand_i  = (const int*)d_in[6];
    float* out = (float*)d_out;
    float* ws  = (float*)d_ws;

    const int BT = in_sizes[0] / (CIN * NNODES);   // 2048

    prep<<<12, 256, 0, stream>>>(conv_w, conv_b, mix_w, mix_b, alpha_p, rand_i, ws);
    hybrid3d_v6<<<BT, 128, 0, stream>>>(x, ws, out);
}